// Round 10
// baseline (183.971 us; speedup 1.0000x reference)
//
#include <hip/hip_runtime.h>

// LinearAttention: B=8, N=16384 (128x128), C=96, H=4, d=24
// prep_w2 (100 blocks): zeroes kvT/ksum finals + packs MFMA-ordered W frags.
// la_k1h (13.9KB LDS, 2048 blocks = 8/CU): HALF-LINE k-GEMM; in-register
//     rope + b64 transposed kqt; kv = K_rope^T V via MFMA; plain coalesced
//     per-block partial stores (NO atomics — r8 proved k1 atomic-RMW-bound;
//     r9 split-K removed it, −9us; r8's 107us was atomics x2 + XCD pinning,
//     NOT the half-line shape — at 8/CU latency-bound k1 wants 2x waves).
// la_reduce (75 blocks): kvT[e][d] (24x32 padded) = inv_n * sum_p kvp;
//     ksum_g = sum_p ksump. Coalesced.
// la_k2 (17.8KB LDS, (256,8)): q-GEMM; rope in epilogue -> qs q_rope bf16
//     pitch 104; z from f32 acc (bucketed shfl reduce); GEMM2 PV (A b128
//     from qs, B = 2x f32x4 from kvT); f16 outs staging; conv with PERMUTED
//     lepe_s (r9 vector layout was ~8-way bank-conflicted: 0.97M->1.55M,
//     k2 48.1->50.7 — restored r7 permute).
// NOTE: cooperative-launch fusion is WRONG (absmax 468) — no redo.
// NOTE: node-count reduction worth ~2 us/node — don't chase.
// NOTE (r3): long live ranges in k2 phase A spill — stay compact.
// NOTE (r5): occupancy > spill in latency-bound k2; keep (256,8).
// NOTE (r7): k2 pinned ~48us, no saturated pipe — latency-bound.

#define NLINE 16384
#define CCH 96
#define KTPF 136   // full-line kqt pitch (u16)
#define KTPH 72    // half-line kqt pitch (u16): 144B rows (16B-mult)
#define QSP 104    // k2 q_rope pitch (u16): 208B rows (16B-mult, b128 frags)
#define OUTP 98    // f16 out-staging pitch (u16): conflict-free
#define THETA_COEF 0.2768273412406135f   // log2(10000)/48
#define LOG2_2PI   2.6514961294723187f   // log2(2*pi)

typedef __attribute__((ext_vector_type(4))) float f32x4;
typedef __attribute__((ext_vector_type(8))) short bf16x8;
typedef __attribute__((ext_vector_type(2))) __fp16 fp16x2;

__device__ __forceinline__ unsigned short f2bf(float f) {
  unsigned int u = __float_as_uint(f);
  u += 0x7FFFu + ((u >> 16) & 1u);          // RNE
  return (unsigned short)(u >> 16);
}
__device__ __forceinline__ float bf2f(unsigned short h) {
  return __uint_as_float(((unsigned int)h) << 16);
}
__device__ __forceinline__ bf16x8 pack_bf8(f32x4 v0, f32x4 v1) {
  bf16x8 r;
  r[0] = (short)f2bf(v0.x); r[1] = (short)f2bf(v0.y);
  r[2] = (short)f2bf(v0.z); r[3] = (short)f2bf(v0.w);
  r[4] = (short)f2bf(v1.x); r[5] = (short)f2bf(v1.y);
  r[6] = (short)f2bf(v1.z); r[7] = (short)f2bf(v1.w);
  return r;
}

// ---------------------------------------------------------------- prep
__global__ void prep_w2(const float* __restrict__ qkw,
                        unsigned short* __restrict__ wfrag,
                        float* __restrict__ kvT) {
  int idx = blockIdx.x * 256 + threadIdx.x;     // 100 blocks -> 25600 threads
  if (idx < 25344) kvT[idx] = 0.0f;             // kvT pads + atomic fallback
  if (idx < 2304) {
    int u = idx;
    int lane = u & 63;
    int nt = (u >> 6) % 6;
    int rest = u / 384;
    int kk = rest % 3, half = rest / 3;
    int lr = lane & 15, q4 = lane >> 4;
    const float* src = qkw + (half * 96 + nt * 16 + lr) * 96 + kk * 32 + q4 * 8;
    unsigned short* dst = wfrag + (size_t)u * 8;
#pragma unroll
    for (int j = 0; j < 8; ++j) dst[j] = f2bf(src[j]);
  }
}

// ---------------------------------------------------------------- kernel 1 (half-line)
// block = (b, seg): tokens seg*64..+63 of batch b; partial stores only.
__global__ __launch_bounds__(256, 8) void la_k1h(
    const float* __restrict__ x, const unsigned short* __restrict__ wfrag,
    const float* __restrict__ qkb, float* __restrict__ kvp,
    float* __restrict__ ksump)
{
  const int tid  = threadIdx.x;
  const int b    = blockIdx.x >> 8;         // batch (segs round-robin XCDs)
  const int seg  = blockIdx.x & 255;
  const int half = seg & 1;                 // w-offset 0/64 for rope position

  __shared__ alignas(16) unsigned short kqt[96 * KTPH];  // 13824 B
  __shared__ float ksum_s[96];

  if (tid < 96) ksum_s[tid] = 0.0f;
  __syncthreads();

  const int wv   = tid >> 6;
  const int lane = tid & 63;
  const int lr   = lane & 15;
  const int q4   = lane >> 4;
  const float* xb = x + ((size_t)b * NLINE + (size_t)seg * 64) * CCH;

  bf16x8 afr[3];
#pragma unroll
  for (int kk = 0; kk < 3; ++kk) {
    const float* ap = xb + (wv * 16 + lr) * CCH + kk * 32 + q4 * 8;
    afr[kk] = pack_bf8(((const f32x4*)ap)[0], ((const f32x4*)ap)[1]);
  }

  float biasv[6];
#pragma unroll
  for (int nt = 0; nt < 6; ++nt) biasv[nt] = qkb[96 + nt * 16 + lr];

  f32x4 acc[6];
#pragma unroll
  for (int nt = 0; nt < 6; ++nt) acc[nt] = (f32x4){0.f, 0.f, 0.f, 0.f};
#pragma unroll
  for (int kk = 0; kk < 3; ++kk) {
#pragma unroll
    for (int nt = 0; nt < 6; ++nt) {
      bf16x8 bf = *(const bf16x8*)&wfrag[(size_t)(((3 + kk) * 6 + nt) * 64 + lane) * 8];
      acc[nt] = __builtin_amdgcn_mfma_f32_16x16x32_bf16(afr[kk], bf, acc[nt], 0, 0, 0);
    }
  }

  // epilogue: bias+elu+1, col-sums, rope (pos = w-coordinate), b64 transposed store
  const int odd = lr & 1;
#pragma unroll
  for (int nt = 0; nt < 6; ++nt) {
    const int col = nt * 16 + lr;
    const float threv = exp2f(-THETA_COEF * (float)(col >> 1) - LOG2_2PI);
    float csum = 0.0f;
    float vv[4];
#pragma unroll
    for (int rg = 0; rg < 4; ++rg) {
      float v = acc[nt][rg] + biasv[nt];
      v = (v > 0.0f) ? (v + 1.0f) : __expf(v);   // elu+1
      csum += v;
      vv[rg] = v;
    }
    atomicAdd(&ksum_s[col], csum);               // LDS atomic (fast)
    unsigned long long pk = 0;
#pragma unroll
    for (int rg = 0; rg < 4; ++rg) {
      float p = __shfl_xor(vv[rg], 1);           // partner col (re<->im)
      int r = half * 64 + wv * 16 + q4 * 4 + rg; // w-coordinate
      float rev = (float)r * threv;
      float sn = __builtin_amdgcn_sinf(rev);
      float cn = __builtin_amdgcn_cosf(rev);
      float o = odd ? (p * sn + vv[rg] * cn)
                    : (vv[rg] * cn - p * sn);
      pk |= (unsigned long long)f2bf(o) << (16 * rg);
    }
    *(unsigned long long*)&kqt[col * KTPH + wv * 16 + q4 * 4] = pk;
  }
  __syncthreads();

  if (tid < 96) ksump[((size_t)b * 256 + seg) * 96 + tid] = ksum_s[tid];

  // kv: wave = head h: D[d][e] = sum_{r<64} k_rope[r][24h+d] * v[r][24h+e]
  const int h = wv;
  f32x4 kvacc[2][2];
#pragma unroll
  for (int mt = 0; mt < 2; ++mt)
#pragma unroll
    for (int nt = 0; nt < 2; ++nt) kvacc[mt][nt] = (f32x4){0.f, 0.f, 0.f, 0.f};

#pragma unroll
  for (int kk = 0; kk < 2; ++kk) {
    const int rbase = kk * 32 + q4 * 8;
    bf16x8 ka[2], vb[2];
#pragma unroll
    for (int mt = 0; mt < 2; ++mt) {
      int c = 24 * h + mt * 16 + lr; if (c > 95) c = 95;   // garbage discarded
      ka[mt] = *(const bf16x8*)&kqt[c * KTPH + rbase];     // ds_read_b128
    }
#pragma unroll
    for (int nt = 0; nt < 2; ++nt) {
      int c = 24 * h + nt * 16 + lr; if (c > 95) c = 95;
#pragma unroll
      for (int j = 0; j < 8; ++j)
        vb[nt][j] = (short)f2bf(xb[(rbase + j) * CCH + c]); // V direct (L2-hot)
    }
#pragma unroll
    for (int mt = 0; mt < 2; ++mt)
#pragma unroll
      for (int nt = 0; nt < 2; ++nt)
        kvacc[mt][nt] = __builtin_amdgcn_mfma_f32_16x16x32_bf16(ka[mt], vb[nt], kvacc[mt][nt], 0, 0, 0);
  }

  float* dst = kvp + ((size_t)(b * 256 + seg) * 4 + h) * 576;
#pragma unroll
  for (int mt = 0; mt < 2; ++mt)
#pragma unroll
    for (int rg = 0; rg < 4; ++rg) {
      int d = mt * 16 + q4 * 4 + rg;
      if (d < 24) {
#pragma unroll
        for (int nt = 0; nt < 2; ++nt) {
          int e = nt * 16 + lr;
          if (e < 24) dst[d * 24 + e] = kvacc[mt][nt][rg];
        }
      }
    }
}

// ---------------------------------------------------------------- kernel 1 (full-line, fallback)
__global__ __launch_bounds__(256, 4) void la_k1(
    const float* __restrict__ x, const unsigned short* __restrict__ wfrag,
    const float* __restrict__ qkb, float* __restrict__ kvT,
    float* __restrict__ ksum_g, float* __restrict__ kvp,
    float* __restrict__ ksump)
{
  const int tid  = threadIdx.x;
  const int b    = blockIdx.x >> 7;
  const int tile = blockIdx.x & 127;

  __shared__ alignas(16) unsigned short kqt[96 * KTPF];  // 26112 B
  __shared__ float ksum_s[96];

  if (tid < 96) ksum_s[tid] = 0.0f;
  __syncthreads();

  const int wave = tid >> 6;
  const int lane = tid & 63;
  const int lr   = lane & 15;
  const int q4   = lane >> 4;
  const int row0 = wave * 32;
  const float* xb = x + ((size_t)b * NLINE + (size_t)tile * 128) * CCH;

  bf16x8 afr[2][3];
#pragma unroll
  for (int mt = 0; mt < 2; ++mt)
#pragma unroll
    for (int kk = 0; kk < 3; ++kk) {
      const float* ap = xb + (row0 + mt * 16 + lr) * CCH + kk * 32 + q4 * 8;
      afr[mt][kk] = pack_bf8(((const f32x4*)ap)[0], ((const f32x4*)ap)[1]);
    }

  float biasv[6];
#pragma unroll
  for (int nt = 0; nt < 6; ++nt) biasv[nt] = qkb[96 + nt * 16 + lr];

  f32x4 acc[2][6];
#pragma unroll
  for (int mt = 0; mt < 2; ++mt)
#pragma unroll
    for (int nt = 0; nt < 6; ++nt) acc[mt][nt] = (f32x4){0.f, 0.f, 0.f, 0.f};

#pragma unroll
  for (int kk = 0; kk < 3; ++kk) {
#pragma unroll
    for (int nt = 0; nt < 6; ++nt) {
      bf16x8 bf = *(const bf16x8*)&wfrag[(size_t)(((3 + kk) * 6 + nt) * 64 + lane) * 8];
      acc[0][nt] = __builtin_amdgcn_mfma_f32_16x16x32_bf16(afr[0][kk], bf, acc[0][nt], 0, 0, 0);
      acc[1][nt] = __builtin_amdgcn_mfma_f32_16x16x32_bf16(afr[1][kk], bf, acc[1][nt], 0, 0, 0);
    }
  }

  const int odd = lr & 1;
#pragma unroll
  for (int nt = 0; nt < 6; ++nt) {
    const int col = nt * 16 + lr;
    const float threv = exp2f(-THETA_COEF * (float)(col >> 1) - LOG2_2PI);
    float csum = 0.0f;
    float vv[2][4];
#pragma unroll
    for (int mt = 0; mt < 2; ++mt)
#pragma unroll
      for (int rg = 0; rg < 4; ++rg) {
        float v = acc[mt][nt][rg] + biasv[nt];
        v = (v > 0.0f) ? (v + 1.0f) : __expf(v);
        csum += v;
        vv[mt][rg] = v;
      }
    atomicAdd(&ksum_s[col], csum);
#pragma unroll
    for (int mt = 0; mt < 2; ++mt) {
      unsigned long long pk = 0;
#pragma unroll
      for (int rg = 0; rg < 4; ++rg) {
        float p = __shfl_xor(vv[mt][rg], 1);
        int r = row0 + mt * 16 + q4 * 4 + rg;
        float rev = (float)r * threv;
        float sn = __builtin_amdgcn_sinf(rev);
        float cn = __builtin_amdgcn_cosf(rev);
        float o = odd ? (p * sn + vv[mt][rg] * cn)
                      : (vv[mt][rg] * cn - p * sn);
        pk |= (unsigned long long)f2bf(o) << (16 * rg);
      }
      *(unsigned long long*)&kqt[col * KTPF + row0 + mt * 16 + q4 * 4] = pk;
    }
  }
  __syncthreads();

  if (tid < 96) {
    if (kvp) ksump[((size_t)b * 128 + tile) * 96 + tid] = ksum_s[tid];
    else     atomicAdd(&ksum_g[b * 96 + tid], ksum_s[tid]);
  }

  const int h = wave;
  f32x4 kvacc[2][2];
#pragma unroll
  for (int mt = 0; mt < 2; ++mt)
#pragma unroll
    for (int nt = 0; nt < 2; ++nt) kvacc[mt][nt] = (f32x4){0.f, 0.f, 0.f, 0.f};

#pragma unroll
  for (int kk = 0; kk < 4; ++kk) {
    const int rbase = kk * 32 + q4 * 8;
    bf16x8 ka[2], vb[2];
#pragma unroll
    for (int mt = 0; mt < 2; ++mt) {
      int c = 24 * h + mt * 16 + lr; if (c > 95) c = 95;
      ka[mt] = *(const bf16x8*)&kqt[c * KTPF + rbase];
    }
#pragma unroll
    for (int nt = 0; nt < 2; ++nt) {
      int c = 24 * h + nt * 16 + lr; if (c > 95) c = 95;
#pragma unroll
      for (int j = 0; j < 8; ++j)
        vb[nt][j] = (short)f2bf(xb[(rbase + j) * CCH + c]);
    }
#pragma unroll
    for (int mt = 0; mt < 2; ++mt)
#pragma unroll
      for (int nt = 0; nt < 2; ++nt)
        kvacc[mt][nt] = __builtin_amdgcn_mfma_f32_16x16x32_bf16(ka[mt], vb[nt], kvacc[mt][nt], 0, 0, 0);
  }

  if (kvp) {
    float* dst = kvp + ((size_t)(b * 128 + tile) * 4 + h) * 576;
#pragma unroll
    for (int mt = 0; mt < 2; ++mt)
#pragma unroll
      for (int rg = 0; rg < 4; ++rg) {
        int d = mt * 16 + q4 * 4 + rg;
        if (d < 24) {
#pragma unroll
          for (int nt = 0; nt < 2; ++nt) {
            int e = nt * 16 + lr;
            if (e < 24) dst[d * 24 + e] = kvacc[mt][nt][rg];
          }
        }
      }
  } else {
    const float inv_n = 1.0f / 16384.0f;
    float* kvbT = kvT + ((size_t)b * 4 + h) * 768;
#pragma unroll
    for (int mt = 0; mt < 2; ++mt)
#pragma unroll
      for (int rg = 0; rg < 4; ++rg) {
        int d = mt * 16 + q4 * 4 + rg;
        if (d < 24) {
#pragma unroll
          for (int nt = 0; nt < 2; ++nt) {
            int e = nt * 16 + lr;
            if (e < 24) atomicAdd(&kvbT[e * 32 + d], kvacc[mt][nt][rg] * inv_n);
          }
        }
      }
  }
}

// ---------------------------------------------------------------- reduce
// P = partials per batch (128 or 256).
__global__ void la_reduce(const float* __restrict__ kvp,
                          const float* __restrict__ ksump,
                          float* __restrict__ kvT,
                          float* __restrict__ ksum_g, int P) {
  int i = blockIdx.x * 256 + threadIdx.x;       // 75 blocks = 19200
  if (i < 18432) {
    int bh = i / 576, de = i - bh * 576;
    int b = bh >> 2, h = bh & 3;
    int d = de / 24, e = de - d * 24;
    const float* src = kvp + ((size_t)b * P * 4 + h) * 576 + de;  // p stride 2304
    float s0 = 0.f, s1 = 0.f, s2 = 0.f, s3 = 0.f;
    for (int p = 0; p < P; p += 4) {
      s0 += src[(size_t)(p + 0) * 2304];
      s1 += src[(size_t)(p + 1) * 2304];
      s2 += src[(size_t)(p + 2) * 2304];
      s3 += src[(size_t)(p + 3) * 2304];
    }
    kvT[(size_t)bh * 768 + e * 32 + d] = ((s0 + s1) + (s2 + s3)) * (1.0f / 16384.0f);
  } else if (i < 19200) {
    int j = i - 18432;
    int b = j / 96, c = j - b * 96;
    const float* src = ksump + (size_t)b * P * 96 + c;            // p stride 96
    float s0 = 0.f, s1 = 0.f, s2 = 0.f, s3 = 0.f;
    for (int p = 0; p < P; p += 4) {
      s0 += src[(p + 0) * 96];
      s1 += src[(p + 1) * 96];
      s2 += src[(p + 2) * 96];
      s3 += src[(p + 3) * 96];
    }
    ksum_g[b * 96 + c] = (s0 + s1) + (s2 + s3);
  }
}

// ---------------------------------------------------------------- kernel 2
__global__ __launch_bounds__(256, 8) void la_k2(
    const float* __restrict__ x, const unsigned short* __restrict__ wfrag,
    const float* __restrict__ qkb, const float* __restrict__ lepe_w,
    const float* __restrict__ lepe_b, const float* __restrict__ kvT,
    const float* __restrict__ ksum_g, float* __restrict__ out)
{
  const int tid = threadIdx.x;
  const int b   = blockIdx.x & 7;           // batch per XCD -> L2 locality
  const int seg = blockIdx.x >> 3;          // 64-token segment (half line)
  const int y   = seg >> 1;                 // image row (block-uniform)

  __shared__ alignas(16) unsigned short qs[64 * QSP];  // 13312 B; reused f16 outs @98
  __shared__ alignas(16) float zs[64 * 4];             // 1024 B z per (token, head)
  __shared__ float lepe_s[9 * 96];                     // 3456 B, PERMUTED rows:
  // lepe_s[tap*96 + (ch&3)*24 + (ch>>2)] — phase-B lanes read {c4,24+c4,48+c4,
  // 72+c4}: conflict-free (r7 proven; vector layout was ~8-way, r9 regression)

  for (int i = tid; i < 864; i += 256) {
    int ch = i / 9, tap = i % 9;
    lepe_s[tap * 96 + (ch & 3) * 24 + (ch >> 2)] = lepe_w[i];
  }

  const int wave = tid >> 6;
  const int lane = tid & 63;
  const int lr   = lane & 15;
  const int q4   = lane >> 4;

  float biasv[6], kmv[6];
#pragma unroll
  for (int nt = 0; nt < 6; ++nt) {
    biasv[nt] = qkb[nt * 16 + lr];
    kmv[nt]   = ksum_g[b * 96 + nt * 16 + lr];
  }

  const float* xb = x + ((size_t)b * NLINE + (size_t)seg * 64) * CCH;
  bf16x8 afrag[3];
#pragma unroll
  for (int kk = 0; kk < 3; ++kk) {
    const float* ap = xb + (wave * 16 + lr) * CCH + kk * 32 + q4 * 8;
    afrag[kk] = pack_bf8(((const f32x4*)ap)[0], ((const f32x4*)ap)[1]);
  }

  f32x4 acc[6];
#pragma unroll
  for (int nt = 0; nt < 6; ++nt) acc[nt] = (f32x4){0.f, 0.f, 0.f, 0.f};
#pragma unroll
  for (int kk = 0; kk < 3; ++kk) {
#pragma unroll
    for (int nt = 0; nt < 6; ++nt) {
      bf16x8 bf = *(const bf16x8*)&wfrag[(size_t)((kk * 6 + nt) * 64 + lane) * 8];
      acc[nt] = __builtin_amdgcn_mfma_f32_16x16x32_bf16(afrag[kk], bf, acc[nt], 0, 0, 0);
    }
  }

  // epilogue: elu+1, head-bucketed z-dot partials (pre-rope, f32), rope,
  // bf16 q_rope store to qs.
  const int odd = lr & 1;
  const int t0  = wave * 16 + q4 * 4;            // + rg
  const int xwb = ((seg & 1) << 6) + t0;         // rope position base
  float d0[4], d1[4], d2[4], d3[4];
#pragma unroll
  for (int rg = 0; rg < 4; ++rg) { d0[rg] = 0.f; d1[rg] = 0.f; d2[rg] = 0.f; d3[rg] = 0.f; }

#pragma unroll
  for (int nt = 0; nt < 6; ++nt) {
    const int col = nt * 16 + lr;
    const float threv = exp2f(-THETA_COEF * (float)(col >> 1) - LOG2_2PI);
    float vv[4];
#pragma unroll
    for (int rg = 0; rg < 4; ++rg) {
      float v = acc[nt][rg] + biasv[nt];
      v = (v > 0.0f) ? (v + 1.0f) : __expf(v);   // elu+1 = q (pre-rope)
      vv[rg] = v;
    }
#pragma unroll
    for (int rg = 0; rg < 4; ++rg) {
      float p = vv[rg] * kmv[nt];
      if (nt == 0)      d0[rg] += p;
      else if (nt == 1) { if (lr < 8) d0[rg] += p; else d1[rg] += p; }
      else if (nt == 2) d1[rg] += p;
      else if (nt == 3) d2[rg] += p;
      else if (nt == 4) { if (lr < 8) d2[rg] += p; else d3[rg] += p; }
      else              d3[rg] += p;
    }
#pragma unroll
    for (int rg = 0; rg < 4; ++rg) {
      float p = __shfl_xor(vv[rg], 1);
      float rev = (float)(xwb + rg) * threv;
      float sn = __builtin_amdgcn_sinf(rev);
      float cn = __builtin_amdgcn_cosf(rev);
      float o = odd ? (p * sn + vv[rg] * cn)
                    : (vv[rg] * cn - p * sn);
      qs[(t0 + rg) * QSP + col] = f2bf(o);
    }
  }

  // reduce dot over the 16 lr lanes, z -> zs
  {
    const float inv_n = 1.0f / 16384.0f;
#pragma unroll
    for (int rg = 0; rg < 4; ++rg) {
      float s0 = d0[rg], s1 = d1[rg], s2 = d2[rg], s3 = d3[rg];
#pragma unroll
      for (int m = 1; m <= 8; m <<= 1) {
        s0 += __shfl_xor(s0, m);
        s1 += __shfl_xor(s1, m);
        s2 += __shfl_xor(s2, m);
        s3 += __shfl_xor(s3, m);
      }
      if (lr == 0) {
        f32x4 zv = { 1.0f / (s0 * inv_n + 1e-6f), 1.0f / (s1 * inv_n + 1e-6f),
                     1.0f / (s2 * inv_n + 1e-6f), 1.0f / (s3 * inv_n + 1e-6f) };
        *(f32x4*)&zs[(t0 + rg) * 4] = zv;
      }
    }
  }
  __syncthreads();

  // GEMM2: wave = head h2. A: b128 frags from qs (pad zeroed in-reg).
  // B: kvT rows (e clamped; padded d cols prep-zeroed) -> 2 f32x4 loads.
  const int h2 = wave;
  bf16x8 qa[4];
#pragma unroll
  for (int m = 0; m < 4; ++m) {
    qa[m] = *(const bf16x8*)&qs[(16 * m + lr) * QSP + 24 * h2 + q4 * 8];
    if (q4 == 3) {
#pragma unroll
      for (int j = 0; j < 8; ++j) qa[m][j] = 0;   // pad region -> 0 (NaN-safe)
    }
  }
  bf16x8 kb[2];
  {
    const float* kvhT = kvT + ((size_t)b * 4 + h2) * 768;
#pragma unroll
    for (int n = 0; n < 2; ++n) {
      int e = n * 16 + lr;
      int er = (e < 24) ? e : 0;                  // clamped rows feed discarded cols
      const f32x4* p = (const f32x4*)&kvhT[er * 32 + q4 * 8];
      kb[n] = pack_bf8(p[0], p[1]);
    }
  }
  f32x4 c2[4][2];
#pragma unroll
  for (int m = 0; m < 4; ++m)
#pragma unroll
    for (int n = 0; n < 2; ++n) c2[m][n] = (f32x4){0.f, 0.f, 0.f, 0.f};
#pragma unroll
  for (int m = 0; m < 4; ++m)
#pragma unroll
    for (int n = 0; n < 2; ++n)
      c2[m][n] = __builtin_amdgcn_mfma_f32_16x16x32_bf16(qa[m], kb[n], c2[m][n], 0, 0, 0);

  __syncthreads();                          // qs frag-reads done before outs overwrite

  // epilogue-2: z scale + lepe_b, stage f16 outs (pitch 98) in qs buffer
  __fp16* outs = (__fp16*)qs;
  {
    float lb0 = lepe_b[24 * h2 + lr];
    float lb1 = (lr < 8) ? lepe_b[24 * h2 + 16 + lr] : 0.0f;
#pragma unroll
    for (int m = 0; m < 4; ++m)
#pragma unroll
      for (int rg = 0; rg < 4; ++rg) {
        int t = 16 * m + q4 * 4 + rg;
        float zv = zs[t * 4 + h2];           // broadcast across lr
        outs[t * OUTP + 24 * h2 + lr] = (__fp16)(c2[m][0][rg] * zv + lb0);
        if (lr < 8)
          outs[t * OUTP + 24 * h2 + 16 + lr] = (__fp16)(c2[m][1][rg] * zv + lb1);
      }
  }
  __syncthreads();

  // phase B: (token, 4ch); coalesced conv reads + flat f32x4 stores
  float* ob = out + ((size_t)b * NLINE + (size_t)seg * 64) * CCH;
  const float* xg = x + (size_t)b * NLINE * CCH;
#pragma unroll
  for (int k = 0; k < 6; ++k) {
    int idx = tid + 256 * k;
    int tl = idx / 24, c4 = idx % 24;
    int ch0 = c4 * 4;
    int xw = ((seg & 1) << 6) + tl;

    fp16x2 p0 = *(const fp16x2*)&outs[tl * OUTP + ch0];
    fp16x2 p1 = *(const fp16x2*)&outs[tl * OUTP + ch0 + 2];
    float r0 = (float)p0[0], r1 = (float)p0[1];
    float r2 = (float)p1[0], r3 = (float)p1[1];

#pragma unroll
    for (int dy = 0; dy < 3; ++dy) {
      int yy = y + dy - 1;
      if (yy < 0 || yy > 127) continue;     // block-uniform
      const float* rowp = xg + ((size_t)yy * 128) * CCH;
#pragma unroll
      for (int dx = 0; dx < 3; ++dx) {
        int xx = xw + dx - 1;
        if (xx < 0 || xx > 127) continue;   // edge lanes only
        f32x4 v = *(const f32x4*)(rowp + xx * CCH + ch0);
        const float* wp = &lepe_s[(dy * 3 + dx) * 96 + c4];  // permuted row
        r0 += wp[0]  * v.x;
        r1 += wp[24] * v.y;
        r2 += wp[48] * v.z;
        r3 += wp[72] * v.w;
      }
    }
    f32x4 o = { r0, r1, r2, r3 };
    ((f32x4*)ob)[idx] = o;
  }
}

// ---------------------------------------------------------------- launch
extern "C" void kernel_launch(void* const* d_in, const int* in_sizes, int n_in,
                              void* d_out, int out_size, void* d_ws, size_t ws_size,
                              hipStream_t stream) {
  const float* x      = (const float*)d_in[0];
  const float* qkw    = (const float*)d_in[1];
  const float* qkb    = (const float*)d_in[2];
  const float* lepe_w = (const float*)d_in[3];
  const float* lepe_b = (const float*)d_in[4];
  float* out = (float*)d_out;

  // ws layout:
  //   wfrag  @ 0         36864 B
  //   kvT    @ 36864     24576 f32 (  98304 B)
  //   ksum_g @ 135168      768 f32 (   3072 B)
  //   kvp    @ 138240  4718592 f32 (18874368 B)  (half-line: 2048 partials)
  //   ksump  @ 19012608 196608 f32 (  786432 B)
  //   total 19799040 B  (full-line tier needs only 9968640 B)
  unsigned short* wfrag = (unsigned short*)d_ws;
  float* kvT    = (float*)((char*)d_ws + 36864);
  float* ksum_g = kvT + 24576;
  float* kvp    = ksum_g + 768;
  float* ksump  = kvp + 4718592;                 // half-line placement
  float* ksumpF = kvp + 2359296;                 // full-line placement

  prep_w2<<<dim3(100), dim3(256), 0, stream>>>(qkw, wfrag, kvT);

  if (ws_size >= 19799040u) {
    la_k1h<<<dim3(2048), dim3(256), 0, stream>>>(x, wfrag, qkb, kvp, ksump);
    la_reduce<<<dim3(75), dim3(256), 0, stream>>>(kvp, ksump, kvT, ksum_g, 256);
  } else if (ws_size >= 9968640u) {
    la_k1<<<dim3(1024), dim3(256), 0, stream>>>(x, wfrag, qkb, kvT, ksum_g,
                                                kvp, ksumpF);
    la_reduce<<<dim3(75), dim3(256), 0, stream>>>(kvp, ksumpF, kvT, ksum_g, 128);
  } else {
    la_k1<<<dim3(1024), dim3(256), 0, stream>>>(x, wfrag, qkb, kvT, ksum_g,
                                                nullptr, nullptr);
  }
  la_k2<<<dim3(2048), dim3(256), 0, stream>>>(x, wfrag, qkb, lepe_w, lepe_b,
                                              kvT, ksum_g, out);
}

// Round 11
// 164.277 us; speedup vs baseline: 1.1199x; 1.1199x over previous
//
#include <hip/hip_runtime.h>

// LinearAttention: B=8, N=16384 (128x128), C=96, H=4, d=24
// prep_w2 (100 blocks): zeroes kvT/ksum finals + packs MFMA-ordered W frags.
// la_k1 (26.1KB LDS, 1024 blocks = 4/CU): FULL-LINE k-GEMM; in-register rope
//     + b64 transposed kqt; kv = K_rope^T V via MFMA; plain coalesced
//     per-block partial stores (NO atomics). r8: k1 was atomic-RMW-bound;
//     r9 split-K fixed it (~37us). r10: half-line 8/CU variant LOST 18us
//     (2x partial traffic + 2x per-block overhead + P=256 reduce) — full-line
//     partial is the proven shape.
// la_reduce (300 blocks, 4-way p-split + shfl combine): kvT[e][d] (24x32
//     padded) = inv_n * sum_p kvp; ksum_g = sum_p ksump. r9's 75-block
//     version was 0.3 blocks/CU latency-bound.
// la_k2 (17.8KB LDS, (256,8)): q-GEMM; rope in epilogue -> qs q_rope bf16
//     pitch 104; z from f32 acc (bucketed shfl reduce); GEMM2 PV (A b128
//     from qs, B = 2x f32x4 from kvT); f16 outs staging; conv with PERMUTED
//     lepe_s (r9 vector layout was ~8-way conflicted; r10 permute = 45.6us).
// NOTE: cooperative-launch fusion is WRONG (absmax 468) — no redo.
// NOTE: node-count reduction worth ~2 us/node — don't chase.
// NOTE (r3): long live ranges in k2 phase A spill — stay compact.
// NOTE (r5): occupancy > spill in latency-bound k2; keep (256,8).
// NOTE (r7): k2 pinned ~48us, no saturated pipe — latency-bound.
// NOTE (r10): occupancy that doubles memory traffic is a net loss (k1h).

#define NLINE 16384
#define CCH 96
#define KTPF 136   // full-line kqt pitch (u16): 272B rows (16B-mult)
#define QSP 104    // k2 q_rope pitch (u16): 208B rows (16B-mult, b128 frags)
#define OUTP 98    // f16 out-staging pitch (u16): conflict-free
#define THETA_COEF 0.2768273412406135f   // log2(10000)/48
#define LOG2_2PI   2.6514961294723187f   // log2(2*pi)

typedef __attribute__((ext_vector_type(4))) float f32x4;
typedef __attribute__((ext_vector_type(8))) short bf16x8;
typedef __attribute__((ext_vector_type(2))) __fp16 fp16x2;

__device__ __forceinline__ unsigned short f2bf(float f) {
  unsigned int u = __float_as_uint(f);
  u += 0x7FFFu + ((u >> 16) & 1u);          // RNE
  return (unsigned short)(u >> 16);
}
__device__ __forceinline__ float bf2f(unsigned short h) {
  return __uint_as_float(((unsigned int)h) << 16);
}
__device__ __forceinline__ bf16x8 pack_bf8(f32x4 v0, f32x4 v1) {
  bf16x8 r;
  r[0] = (short)f2bf(v0.x); r[1] = (short)f2bf(v0.y);
  r[2] = (short)f2bf(v0.z); r[3] = (short)f2bf(v0.w);
  r[4] = (short)f2bf(v1.x); r[5] = (short)f2bf(v1.y);
  r[6] = (short)f2bf(v1.z); r[7] = (short)f2bf(v1.w);
  return r;
}

// ---------------------------------------------------------------- prep
__global__ void prep_w2(const float* __restrict__ qkw,
                        unsigned short* __restrict__ wfrag,
                        float* __restrict__ kvT) {
  int idx = blockIdx.x * 256 + threadIdx.x;     // 100 blocks -> 25600 threads
  if (idx < 25344) kvT[idx] = 0.0f;             // kvT pads + atomic fallback
  if (idx < 2304) {
    int u = idx;
    int lane = u & 63;
    int nt = (u >> 6) % 6;
    int rest = u / 384;
    int kk = rest % 3, half = rest / 3;
    int lr = lane & 15, q4 = lane >> 4;
    const float* src = qkw + (half * 96 + nt * 16 + lr) * 96 + kk * 32 + q4 * 8;
    unsigned short* dst = wfrag + (size_t)u * 8;
#pragma unroll
    for (int j = 0; j < 8; ++j) dst[j] = f2bf(src[j]);
  }
}

// ---------------------------------------------------------------- kernel 1
// full-line tile (128 tokens); kvp!=nullptr -> partial-store path (no atomics)
__global__ __launch_bounds__(256, 4) void la_k1(
    const float* __restrict__ x, const unsigned short* __restrict__ wfrag,
    const float* __restrict__ qkb, float* __restrict__ kvT,
    float* __restrict__ ksum_g, float* __restrict__ kvp,
    float* __restrict__ ksump)
{
  const int tid  = threadIdx.x;
  const int b    = blockIdx.x >> 7;         // batch spread over XCDs
  const int tile = blockIdx.x & 127;        // image line y

  __shared__ alignas(16) unsigned short kqt[96 * KTPF];  // 26112 B
  __shared__ float ksum_s[96];

  if (tid < 96) ksum_s[tid] = 0.0f;
  __syncthreads();

  const int wave = tid >> 6;
  const int lane = tid & 63;
  const int lr   = lane & 15;
  const int q4   = lane >> 4;
  const int row0 = wave * 32;
  const float* xb = x + ((size_t)b * NLINE + (size_t)tile * 128) * CCH;

  bf16x8 afr[2][3];
#pragma unroll
  for (int mt = 0; mt < 2; ++mt)
#pragma unroll
    for (int kk = 0; kk < 3; ++kk) {
      const float* ap = xb + (row0 + mt * 16 + lr) * CCH + kk * 32 + q4 * 8;
      afr[mt][kk] = pack_bf8(((const f32x4*)ap)[0], ((const f32x4*)ap)[1]);
    }

  float biasv[6];
#pragma unroll
  for (int nt = 0; nt < 6; ++nt) biasv[nt] = qkb[96 + nt * 16 + lr];

  f32x4 acc[2][6];
#pragma unroll
  for (int mt = 0; mt < 2; ++mt)
#pragma unroll
    for (int nt = 0; nt < 6; ++nt) acc[mt][nt] = (f32x4){0.f, 0.f, 0.f, 0.f};

#pragma unroll
  for (int kk = 0; kk < 3; ++kk) {
#pragma unroll
    for (int nt = 0; nt < 6; ++nt) {
      bf16x8 bf = *(const bf16x8*)&wfrag[(size_t)(((3 + kk) * 6 + nt) * 64 + lane) * 8];
      acc[0][nt] = __builtin_amdgcn_mfma_f32_16x16x32_bf16(afr[0][kk], bf, acc[0][nt], 0, 0, 0);
      acc[1][nt] = __builtin_amdgcn_mfma_f32_16x16x32_bf16(afr[1][kk], bf, acc[1][nt], 0, 0, 0);
    }
  }

  // epilogue: bias+elu+1, col-sums, in-register rope, b64 transposed store
  const int odd = lr & 1;
#pragma unroll
  for (int nt = 0; nt < 6; ++nt) {
    const int col = nt * 16 + lr;
    const float threv = exp2f(-THETA_COEF * (float)(col >> 1) - LOG2_2PI);
    float csum = 0.0f;
    float vv[2][4];
#pragma unroll
    for (int mt = 0; mt < 2; ++mt)
#pragma unroll
      for (int rg = 0; rg < 4; ++rg) {
        float v = acc[mt][nt][rg] + biasv[nt];
        v = (v > 0.0f) ? (v + 1.0f) : __expf(v);   // elu+1
        csum += v;
        vv[mt][rg] = v;
      }
    atomicAdd(&ksum_s[col], csum);                 // LDS atomic (fast)
#pragma unroll
    for (int mt = 0; mt < 2; ++mt) {
      unsigned long long pk = 0;
#pragma unroll
      for (int rg = 0; rg < 4; ++rg) {
        float p = __shfl_xor(vv[mt][rg], 1);       // partner col (re<->im)
        int r = row0 + mt * 16 + q4 * 4 + rg;
        float rev = (float)r * threv;
        float sn = __builtin_amdgcn_sinf(rev);
        float cn = __builtin_amdgcn_cosf(rev);
        float o = odd ? (p * sn + vv[mt][rg] * cn)
                      : (vv[mt][rg] * cn - p * sn);
        pk |= (unsigned long long)f2bf(o) << (16 * rg);
      }
      *(unsigned long long*)&kqt[col * KTPF + row0 + mt * 16 + q4 * 4] = pk;
    }
  }
  __syncthreads();

  if (tid < 96) {
    if (kvp) ksump[((size_t)b * 128 + tile) * 96 + tid] = ksum_s[tid];
    else     atomicAdd(&ksum_g[b * 96 + tid], ksum_s[tid]);
  }

  // kv: wave = head h: D[d][e] = sum_r k_rope[r][24h+d] * v[r][24h+e]
  const int h = wave;
  f32x4 kvacc[2][2];
#pragma unroll
  for (int mt = 0; mt < 2; ++mt)
#pragma unroll
    for (int nt = 0; nt < 2; ++nt) kvacc[mt][nt] = (f32x4){0.f, 0.f, 0.f, 0.f};

#pragma unroll
  for (int kk = 0; kk < 4; ++kk) {
    const int rbase = kk * 32 + q4 * 8;
    bf16x8 ka[2], vb[2];
#pragma unroll
    for (int mt = 0; mt < 2; ++mt) {
      int c = 24 * h + mt * 16 + lr; if (c > 95) c = 95;   // garbage discarded
      ka[mt] = *(const bf16x8*)&kqt[c * KTPF + rbase];     // ds_read_b128
    }
#pragma unroll
    for (int nt = 0; nt < 2; ++nt) {
      int c = 24 * h + nt * 16 + lr; if (c > 95) c = 95;
#pragma unroll
      for (int j = 0; j < 8; ++j)
        vb[nt][j] = (short)f2bf(xb[(rbase + j) * CCH + c]); // V direct (L2-hot)
    }
#pragma unroll
    for (int mt = 0; mt < 2; ++mt)
#pragma unroll
      for (int nt = 0; nt < 2; ++nt)
        kvacc[mt][nt] = __builtin_amdgcn_mfma_f32_16x16x32_bf16(ka[mt], vb[nt], kvacc[mt][nt], 0, 0, 0);
  }

  if (kvp) {
    float* dst = kvp + ((size_t)(b * 128 + tile) * 4 + h) * 576;
#pragma unroll
    for (int mt = 0; mt < 2; ++mt)
#pragma unroll
      for (int rg = 0; rg < 4; ++rg) {
        int d = mt * 16 + q4 * 4 + rg;
        if (d < 24) {
#pragma unroll
          for (int nt = 0; nt < 2; ++nt) {
            int e = nt * 16 + lr;
            if (e < 24) dst[d * 24 + e] = kvacc[mt][nt][rg];
          }
        }
      }
  } else {
    const float inv_n = 1.0f / 16384.0f;
    float* kvbT = kvT + ((size_t)b * 4 + h) * 768;
#pragma unroll
    for (int mt = 0; mt < 2; ++mt)
#pragma unroll
      for (int rg = 0; rg < 4; ++rg) {
        int d = mt * 16 + q4 * 4 + rg;
        if (d < 24) {
#pragma unroll
          for (int nt = 0; nt < 2; ++nt) {
            int e = nt * 16 + lr;
            if (e < 24) atomicAdd(&kvbT[e * 32 + d], kvacc[mt][nt][rg] * inv_n);
          }
        }
      }
  }
}

// ---------------------------------------------------------------- reduce
// 4-way p-split: idx = (out_i << 2) | quarter; each sums 32 of 128 partials,
// combined via shfl_xor(1,2) within the 4-lane group. 300 blocks = 76800 thr.
__global__ void la_reduce(const float* __restrict__ kvp,
                          const float* __restrict__ ksump,
                          float* __restrict__ kvT,
                          float* __restrict__ ksum_g) {
  int idx = blockIdx.x * 256 + threadIdx.x;
  int i = idx >> 2, qt = idx & 3;
  if (i >= 19200) return;
  float s = 0.0f;
  if (i < 18432) {
    int bh = i / 576, de = i - bh * 576;
    const float* src = kvp + ((size_t)(bh >> 2) * 512 + (bh & 3)) * 576 + de
                           + (size_t)qt * 32 * 2304;     // p stride 2304 f32
#pragma unroll 8
    for (int p = 0; p < 32; ++p) s += src[(size_t)p * 2304];
  } else {
    int j = i - 18432;                                   // = b*96 + c
    const float* src = ksump + (size_t)(j / 96) * 128 * 96 + (j % 96)
                             + qt * 32 * 96;             // p stride 96 f32
#pragma unroll 8
    for (int p = 0; p < 32; ++p) s += src[p * 96];
  }
  s += __shfl_xor(s, 1);
  s += __shfl_xor(s, 2);
  if (qt == 0) {
    if (i < 18432) {
      int bh = i / 576, de = i - bh * 576;
      int d = de / 24, e = de - d * 24;
      kvT[(size_t)bh * 768 + e * 32 + d] = s * (1.0f / 16384.0f);
    } else {
      ksum_g[i - 18432] = s;
    }
  }
}

// ---------------------------------------------------------------- kernel 2
__global__ __launch_bounds__(256, 8) void la_k2(
    const float* __restrict__ x, const unsigned short* __restrict__ wfrag,
    const float* __restrict__ qkb, const float* __restrict__ lepe_w,
    const float* __restrict__ lepe_b, const float* __restrict__ kvT,
    const float* __restrict__ ksum_g, float* __restrict__ out)
{
  const int tid = threadIdx.x;
  const int b   = blockIdx.x & 7;           // batch per XCD -> L2 locality
  const int seg = blockIdx.x >> 3;          // 64-token segment (half line)
  const int y   = seg >> 1;                 // image row (block-uniform)

  __shared__ alignas(16) unsigned short qs[64 * QSP];  // 13312 B; reused f16 outs @98
  __shared__ alignas(16) float zs[64 * 4];             // 1024 B z per (token, head)
  __shared__ float lepe_s[9 * 96];                     // 3456 B, PERMUTED rows:
  // lepe_s[tap*96 + (ch&3)*24 + (ch>>2)] — phase-B lanes read {c4,24+c4,48+c4,
  // 72+c4}: conflict-free (r7/r10 proven; vector layout was ~8-way, r9 regr.)

  for (int i = tid; i < 864; i += 256) {
    int ch = i / 9, tap = i % 9;
    lepe_s[tap * 96 + (ch & 3) * 24 + (ch >> 2)] = lepe_w[i];
  }

  const int wave = tid >> 6;
  const int lane = tid & 63;
  const int lr   = lane & 15;
  const int q4   = lane >> 4;

  float biasv[6], kmv[6];
#pragma unroll
  for (int nt = 0; nt < 6; ++nt) {
    biasv[nt] = qkb[nt * 16 + lr];
    kmv[nt]   = ksum_g[b * 96 + nt * 16 + lr];
  }

  const float* xb = x + ((size_t)b * NLINE + (size_t)seg * 64) * CCH;
  bf16x8 afrag[3];
#pragma unroll
  for (int kk = 0; kk < 3; ++kk) {
    const float* ap = xb + (wave * 16 + lr) * CCH + kk * 32 + q4 * 8;
    afrag[kk] = pack_bf8(((const f32x4*)ap)[0], ((const f32x4*)ap)[1]);
  }

  f32x4 acc[6];
#pragma unroll
  for (int nt = 0; nt < 6; ++nt) acc[nt] = (f32x4){0.f, 0.f, 0.f, 0.f};
#pragma unroll
  for (int kk = 0; kk < 3; ++kk) {
#pragma unroll
    for (int nt = 0; nt < 6; ++nt) {
      bf16x8 bf = *(const bf16x8*)&wfrag[(size_t)((kk * 6 + nt) * 64 + lane) * 8];
      acc[nt] = __builtin_amdgcn_mfma_f32_16x16x32_bf16(afrag[kk], bf, acc[nt], 0, 0, 0);
    }
  }

  // epilogue: elu+1, head-bucketed z-dot partials (pre-rope, f32), rope,
  // bf16 q_rope store to qs.
  const int odd = lr & 1;
  const int t0  = wave * 16 + q4 * 4;            // + rg
  const int xwb = ((seg & 1) << 6) + t0;         // rope position base
  float d0[4], d1[4], d2[4], d3[4];
#pragma unroll
  for (int rg = 0; rg < 4; ++rg) { d0[rg] = 0.f; d1[rg] = 0.f; d2[rg] = 0.f; d3[rg] = 0.f; }

#pragma unroll
  for (int nt = 0; nt < 6; ++nt) {
    const int col = nt * 16 + lr;
    const float threv = exp2f(-THETA_COEF * (float)(col >> 1) - LOG2_2PI);
    float vv[4];
#pragma unroll
    for (int rg = 0; rg < 4; ++rg) {
      float v = acc[nt][rg] + biasv[nt];
      v = (v > 0.0f) ? (v + 1.0f) : __expf(v);   // elu+1 = q (pre-rope)
      vv[rg] = v;
    }
#pragma unroll
    for (int rg = 0; rg < 4; ++rg) {
      float p = vv[rg] * kmv[nt];
      if (nt == 0)      d0[rg] += p;
      else if (nt == 1) { if (lr < 8) d0[rg] += p; else d1[rg] += p; }
      else if (nt == 2) d1[rg] += p;
      else if (nt == 3) d2[rg] += p;
      else if (nt == 4) { if (lr < 8) d2[rg] += p; else d3[rg] += p; }
      else              d3[rg] += p;
    }
#pragma unroll
    for (int rg = 0; rg < 4; ++rg) {
      float p = __shfl_xor(vv[rg], 1);
      float rev = (float)(xwb + rg) * threv;
      float sn = __builtin_amdgcn_sinf(rev);
      float cn = __builtin_amdgcn_cosf(rev);
      float o = odd ? (p * sn + vv[rg] * cn)
                    : (vv[rg] * cn - p * sn);
      qs[(t0 + rg) * QSP + col] = f2bf(o);
    }
  }

  // reduce dot over the 16 lr lanes, z -> zs
  {
    const float inv_n = 1.0f / 16384.0f;
#pragma unroll
    for (int rg = 0; rg < 4; ++rg) {
      float s0 = d0[rg], s1 = d1[rg], s2 = d2[rg], s3 = d3[rg];
#pragma unroll
      for (int m = 1; m <= 8; m <<= 1) {
        s0 += __shfl_xor(s0, m);
        s1 += __shfl_xor(s1, m);
        s2 += __shfl_xor(s2, m);
        s3 += __shfl_xor(s3, m);
      }
      if (lr == 0) {
        f32x4 zv = { 1.0f / (s0 * inv_n + 1e-6f), 1.0f / (s1 * inv_n + 1e-6f),
                     1.0f / (s2 * inv_n + 1e-6f), 1.0f / (s3 * inv_n + 1e-6f) };
        *(f32x4*)&zs[(t0 + rg) * 4] = zv;
      }
    }
  }
  __syncthreads();

  // GEMM2: wave = head h2. A: b128 frags from qs (pad zeroed in-reg).
  // B: kvT rows (e clamped; padded d cols prep-zeroed) -> 2 f32x4 loads.
  const int h2 = wave;
  bf16x8 qa[4];
#pragma unroll
  for (int m = 0; m < 4; ++m) {
    qa[m] = *(const bf16x8*)&qs[(16 * m + lr) * QSP + 24 * h2 + q4 * 8];
    if (q4 == 3) {
#pragma unroll
      for (int j = 0; j < 8; ++j) qa[m][j] = 0;   // pad region -> 0 (NaN-safe)
    }
  }
  bf16x8 kb[2];
  {
    const float* kvhT = kvT + ((size_t)b * 4 + h2) * 768;
#pragma unroll
    for (int n = 0; n < 2; ++n) {
      int e = n * 16 + lr;
      int er = (e < 24) ? e : 0;                  // clamped rows feed discarded cols
      const f32x4* p = (const f32x4*)&kvhT[er * 32 + q4 * 8];
      kb[n] = pack_bf8(p[0], p[1]);
    }
  }
  f32x4 c2[4][2];
#pragma unroll
  for (int m = 0; m < 4; ++m)
#pragma unroll
    for (int n = 0; n < 2; ++n) c2[m][n] = (f32x4){0.f, 0.f, 0.f, 0.f};
#pragma unroll
  for (int m = 0; m < 4; ++m)
#pragma unroll
    for (int n = 0; n < 2; ++n)
      c2[m][n] = __builtin_amdgcn_mfma_f32_16x16x32_bf16(qa[m], kb[n], c2[m][n], 0, 0, 0);

  __syncthreads();                          // qs frag-reads done before outs overwrite

  // epilogue-2: z scale + lepe_b, stage f16 outs (pitch 98) in qs buffer
  __fp16* outs = (__fp16*)qs;
  {
    float lb0 = lepe_b[24 * h2 + lr];
    float lb1 = (lr < 8) ? lepe_b[24 * h2 + 16 + lr] : 0.0f;
#pragma unroll
    for (int m = 0; m < 4; ++m)
#pragma unroll
      for (int rg = 0; rg < 4; ++rg) {
        int t = 16 * m + q4 * 4 + rg;
        float zv = zs[t * 4 + h2];           // broadcast across lr
        outs[t * OUTP + 24 * h2 + lr] = (__fp16)(c2[m][0][rg] * zv + lb0);
        if (lr < 8)
          outs[t * OUTP + 24 * h2 + 16 + lr] = (__fp16)(c2[m][1][rg] * zv + lb1);
      }
  }
  __syncthreads();

  // phase B: (token, 4ch); coalesced conv reads + flat f32x4 stores
  float* ob = out + ((size_t)b * NLINE + (size_t)seg * 64) * CCH;
  const float* xg = x + (size_t)b * NLINE * CCH;
#pragma unroll
  for (int k = 0; k < 6; ++k) {
    int idx = tid + 256 * k;
    int tl = idx / 24, c4 = idx % 24;
    int ch0 = c4 * 4;
    int xw = ((seg & 1) << 6) + tl;

    fp16x2 p0 = *(const fp16x2*)&outs[tl * OUTP + ch0];
    fp16x2 p1 = *(const fp16x2*)&outs[tl * OUTP + ch0 + 2];
    float r0 = (float)p0[0], r1 = (float)p0[1];
    float r2 = (float)p1[0], r3 = (float)p1[1];

#pragma unroll
    for (int dy = 0; dy < 3; ++dy) {
      int yy = y + dy - 1;
      if (yy < 0 || yy > 127) continue;     // block-uniform
      const float* rowp = xg + ((size_t)yy * 128) * CCH;
#pragma unroll
      for (int dx = 0; dx < 3; ++dx) {
        int xx = xw + dx - 1;
        if (xx < 0 || xx > 127) continue;   // edge lanes only
        f32x4 v = *(const f32x4*)(rowp + xx * CCH + ch0);
        const float* wp = &lepe_s[(dy * 3 + dx) * 96 + c4];  // permuted row
        r0 += wp[0]  * v.x;
        r1 += wp[24] * v.y;
        r2 += wp[48] * v.z;
        r3 += wp[72] * v.w;
      }
    }
    f32x4 o = { r0, r1, r2, r3 };
    ((f32x4*)ob)[idx] = o;
  }
}

// ---------------------------------------------------------------- launch
extern "C" void kernel_launch(void* const* d_in, const int* in_sizes, int n_in,
                              void* d_out, int out_size, void* d_ws, size_t ws_size,
                              hipStream_t stream) {
  const float* x      = (const float*)d_in[0];
  const float* qkw    = (const float*)d_in[1];
  const float* qkb    = (const float*)d_in[2];
  const float* lepe_w = (const float*)d_in[3];
  const float* lepe_b = (const float*)d_in[4];
  float* out = (float*)d_out;

  // ws layout:
  //   wfrag  @ 0        36864 B
  //   kvT    @ 36864    24576 f32 ( 98304 B)
  //   ksum_g @ 135168     768 f32 (  3072 B)
  //   kvp    @ 138240 2359296 f32 (9437184 B)  per-line kv partials (128/batch)
  //   ksump  @ 9575424  98304 f32 (393216 B)   per-line ksum partials
  //   total 9968640 B
  unsigned short* wfrag = (unsigned short*)d_ws;
  float* kvT    = (float*)((char*)d_ws + 36864);
  float* ksum_g = kvT + 24576;
  float* kvp    = ksum_g + 768;
  float* ksump  = kvp + 2359296;

  const bool partial = (ws_size >= 9968640u);

  prep_w2<<<dim3(100), dim3(256), 0, stream>>>(qkw, wfrag, kvT);
  la_k1<<<dim3(1024), dim3(256), 0, stream>>>(x, wfrag, qkb, kvT, ksum_g,
                                              partial ? kvp : nullptr,
                                              partial ? ksump : nullptr);
  if (partial)
    la_reduce<<<dim3(300), dim3(256), 0, stream>>>(kvp, ksump, kvT, ksum_g);
  la_k2<<<dim3(2048), dim3(256), 0, stream>>>(x, wfrag, qkb, lepe_w, lepe_b,
                                              kvT, ksum_g, out);
}